// Round 11
// baseline (773.042 us; speedup 1.0000x reference)
//
#include <hip/hip_runtime.h>
#include <hip/hip_bf16.h>
#include <math.h>

#define D_MODEL 128
#define HW      1024
#define DEPTH   4
#define NIMG    128   // B*T
#define B_      8
#define T_      16
#define LN_EPSF 1e-5f
#define TLN     131072   // elements per image (128*1024)
#define PS      1033     // scan LDS plane stride (dwords)

typedef short  s8  __attribute__((ext_vector_type(8)));
typedef ushort us8 __attribute__((ext_vector_type(8)));
typedef ushort us4 __attribute__((ext_vector_type(4)));
typedef float  f4  __attribute__((ext_vector_type(4)));

#define MFMA __builtin_amdgcn_mfma_f32_16x16x32_bf16

__device__ __forceinline__ float sig_(float x) { return 1.0f / (1.0f + __expf(-x)); }
__device__ __forceinline__ float tanh_(float x) { return 2.0f * sig_(2.0f * x) - 1.0f; }
__device__ __forceinline__ ushort f2b(float f) {
    __hip_bfloat16 h = __float2bfloat16(f);
    return *reinterpret_cast<ushort*>(&h);
}
__device__ __forceinline__ float b2f(ushort u) {
    __hip_bfloat16 h = *reinterpret_cast<__hip_bfloat16*>(&u);
    return __bfloat162float(h);
}

// ---------------------------------------------------------------------------
// wconv: fp32 -> bf16 weight pre-conversion
// ---------------------------------------------------------------------------
__global__ __launch_bounds__(256) void wconv_kernel(
    const float* __restrict__ src, ushort* __restrict__ dst, int n)
{
    int i = blockIdx.x * 256 + threadIdx.x;
    if (i < n) dst[i] = f2b(src[i]);
}

// ---------------------------------------------------------------------------
// 3-gate MFMA from LDS tile Xs[q][d]; stores iu/og to TILED layout:
// TL(d,q) = (d>>3)*8192 + q*8 + (d&7).
// TWO-PHASE: (U,I) accumulate+store, then (O) — halves peak accumulator regs.
// ---------------------------------------------------------------------------
__device__ __forceinline__ void gates_from_lds_TL(
    const ushort (*Xs)[136], const ushort* __restrict__ Wi,
    ushort* __restrict__ iu, ushort* __restrict__ og,
    size_t nbase, int q0, int tid)
{
    const int lane = tid & 63, wv = tid >> 6, grp = lane >> 4, lrow = lane & 15;
    const int ch0 = wv * 32;

    // ---- phase 1: U and I gates ----
    {
        f4 aU[2][4], aI[2][4];
        #pragma unroll
        for (int nt = 0; nt < 2; ++nt)
            #pragma unroll
            for (int qt = 0; qt < 4; ++qt) { aU[nt][qt] = (f4)0.f; aI[nt][qt] = (f4)0.f; }

        #pragma unroll
        for (int kk = 0; kk < 4; ++kk) {
            const int kb = kk * 32 + grp * 8;
            s8 xb[4], wu[2], wi[2];
            #pragma unroll
            for (int qt = 0; qt < 4; ++qt)
                xb[qt] = *reinterpret_cast<const s8*>(&Xs[qt * 16 + lrow][kb]);
            #pragma unroll
            for (int nt = 0; nt < 2; ++nt) {
                const int e = ch0 + nt * 16 + lrow;
                wu[nt] = *reinterpret_cast<const s8*>(Wi + (size_t)e * D_MODEL + kb);
                wi[nt] = *reinterpret_cast<const s8*>(Wi + (size_t)(e + 128) * D_MODEL + kb);
            }
            #pragma unroll
            for (int nt = 0; nt < 2; ++nt)
                #pragma unroll
                for (int qt = 0; qt < 4; ++qt) {
                    aU[nt][qt] = MFMA(wu[nt], xb[qt], aU[nt][qt], 0, 0, 0);
                    aI[nt][qt] = MFMA(wi[nt], xb[qt], aI[nt][qt], 0, 0, 0);
                }
        }
        #pragma unroll
        for (int nt = 0; nt < 2; ++nt)
            #pragma unroll
            for (int qt = 0; qt < 4; ++qt) {
                const int ch = ch0 + nt * 16 + grp * 4;
                const int q  = q0 + qt * 16 + lrow;
                const size_t off = nbase + (size_t)(ch >> 3) * 8192 + (size_t)q * 8 + (ch & 7);
                us4 piu;
                #pragma unroll
                for (int i = 0; i < 4; ++i)
                    piu[i] = f2b(sig_(aI[nt][qt][i]) * tanh_(aU[nt][qt][i]));
                *reinterpret_cast<us4*>(iu + off) = piu;
            }
    }

    // ---- phase 2: O gate ----
    {
        f4 aO[2][4];
        #pragma unroll
        for (int nt = 0; nt < 2; ++nt)
            #pragma unroll
            for (int qt = 0; qt < 4; ++qt) aO[nt][qt] = (f4)0.f;

        #pragma unroll
        for (int kk = 0; kk < 4; ++kk) {
            const int kb = kk * 32 + grp * 8;
            s8 xb[4], wo[2];
            #pragma unroll
            for (int qt = 0; qt < 4; ++qt)
                xb[qt] = *reinterpret_cast<const s8*>(&Xs[qt * 16 + lrow][kb]);
            #pragma unroll
            for (int nt = 0; nt < 2; ++nt)
                wo[nt] = *reinterpret_cast<const s8*>(Wi + (size_t)(ch0 + nt * 16 + lrow + 256) * D_MODEL + kb);
            #pragma unroll
            for (int nt = 0; nt < 2; ++nt)
                #pragma unroll
                for (int qt = 0; qt < 4; ++qt)
                    aO[nt][qt] = MFMA(wo[nt], xb[qt], aO[nt][qt], 0, 0, 0);
        }
        #pragma unroll
        for (int nt = 0; nt < 2; ++nt)
            #pragma unroll
            for (int qt = 0; qt < 4; ++qt) {
                const int ch = ch0 + nt * 16 + grp * 4;
                const int q  = q0 + qt * 16 + lrow;
                const size_t off = nbase + (size_t)(ch >> 3) * 8192 + (size_t)q * 8 + (ch & 7);
                us4 pog;
                #pragma unroll
                for (int i = 0; i < 4; ++i)
                    pog[i] = f2b(sig_(aO[nt][qt][i]));
                *reinterpret_cast<us4*>(og + off) = pog;
            }
    }
}

// ---------------------------------------------------------------------------
// gates_f32: layer-0 spatial gates from fp32 tok [n][d][q].
// ---------------------------------------------------------------------------
__global__ __launch_bounds__(256, 3) void gates_f32_kernel(
    const float* __restrict__ in, const ushort* __restrict__ Wi,
    ushort* __restrict__ iu, ushort* __restrict__ og)
{
    __shared__ ushort Xs[64][136];
    const int n   = blockIdx.x >> 4;
    const int q0  = (blockIdx.x & 15) << 6;
    const int tid = threadIdx.x;
    const size_t nbase = (size_t)n * TLN;

    {
        const float* inb = in + nbase + q0;
        const int q = tid & 63, dh0 = tid >> 6;
        for (int it = 0; it < 4; ++it) {
            const int dh = dh0 + it * 4;
            s8 pk;
            #pragma unroll
            for (int j = 0; j < 8; ++j)
                pk[j] = (short)f2b(inb[(size_t)(dh * 8 + j) * HW + q]);
            *reinterpret_cast<s8*>(&Xs[q][dh * 8]) = pk;
        }
    }
    __syncthreads();
    gates_from_lds_TL(Xs, Wi, iu, og, nbase, q0, tid);
}

// ---------------------------------------------------------------------------
// scan2d: block=(n, d-octet). og tile PREFETCHED into regs at entry (hides
// its latency under the scan phases). Row scans -> R; col scans + R -> S;
// writes G = og * S * 0.25 (bf16, tiled). In-place over iu buffer.
// ---------------------------------------------------------------------------
__global__ __launch_bounds__(256, 2) void scan2d_kernel(
    ushort* bufG /* in: iu, out: G */, const ushort* __restrict__ og,
    const float* __restrict__ Av)
{
    __shared__ float P[8 * PS];
    __shared__ float R[8 * PS];
    const int n   = blockIdx.x >> 4;
    const int oct = blockIdx.x & 15;
    const int tid = threadIdx.x;
    const size_t base = (size_t)n * TLN + (size_t)oct * 8192;

    // prefetch og tile (consumed in phase 4)
    us8 ogv[4];
    #pragma unroll
    for (int it = 0; it < 4; ++it)
        ogv[it] = *reinterpret_cast<const us8*>(og + base + (size_t)(it * 256 + tid) * 8);

    for (int it = 0; it < 4; ++it) {
        const int p  = it * 256 + tid;
        const int sw = p ^ (((p >> 5) & 7) << 2);
        us8 v = *reinterpret_cast<const us8*>(bufG + base + (size_t)p * 8);
        #pragma unroll
        for (int dc = 0; dc < 8; ++dc) P[dc * PS + sw] = b2f(v[dc]);
    }
    __syncthreads();

    const int dc  = tid & 7;
    const int row = tid >> 3;
    const float a = fminf(__expf(Av[oct * 8 + dc]), 0.999f);

    {
        const int swb = (row * 32) ^ (((row & 7) << 2));
        float x[32], r[32];
        #pragma unroll
        for (int j = 0; j < 32; ++j) x[j] = P[dc * PS + (swb ^ j)];
        float s = 0.f;
        #pragma unroll
        for (int j = 0; j < 32; ++j) { s = fmaf(a, s, x[j]); r[j] = s; }
        s = 0.f;
        #pragma unroll
        for (int j = 31; j >= 0; --j) { s = fmaf(a, s, x[j]); r[j] += s; }
        #pragma unroll
        for (int j = 0; j < 32; ++j) R[dc * PS + (swb ^ j)] = r[j];
    }
    __syncthreads();

    {
        float x[32], t[32];
        #pragma unroll
        for (int i = 0; i < 32; ++i) {
            const int p = i * 32 + row;
            x[i] = P[dc * PS + (p ^ ((i & 7) << 2))];
        }
        float s = 0.f;
        #pragma unroll
        for (int i = 0; i < 32; ++i) { s = fmaf(a, s, x[i]); t[i] = s; }
        s = 0.f;
        #pragma unroll
        for (int i = 31; i >= 0; --i) { s = fmaf(a, s, x[i]); t[i] += s; }
        #pragma unroll
        for (int i = 0; i < 32; ++i) {
            const int idx = dc * PS + ((i * 32 + row) ^ ((i & 7) << 2));
            P[idx] = t[i] + R[idx];
        }
    }
    __syncthreads();

    for (int it = 0; it < 4; ++it) {
        const int p  = it * 256 + tid;
        const int sw = p ^ (((p >> 5) & 7) << 2);
        us8 w;
        #pragma unroll
        for (int d2 = 0; d2 < 8; ++d2)
            w[d2] = f2b(b2f(ogv[it][d2]) * P[d2 * PS + sw] * 0.25f);
        *reinterpret_cast<us8*>(bufG + base + (size_t)p * 8) = w;
    }
}

// ---------------------------------------------------------------------------
// fusedA: xs = WoS @ G (direct-global TL fragments, wave owns 16-q subtile),
// xs -> LDS, then temporal 3-gate GEMM -> iu_T/og_T (TL). 2048 blocks.
// ---------------------------------------------------------------------------
__global__ __launch_bounds__(256, 3) void fusedA_kernel(
    ushort* bufA /* in: G, out: iu_T */, ushort* bufB /* out: og_T */,
    const ushort* __restrict__ WoS, const ushort* __restrict__ WiT)
{
    __shared__ ushort Xs[64][136];
    const int n   = blockIdx.x >> 4;
    const int q0  = (blockIdx.x & 15) << 6;
    const int tid = threadIdx.x;
    const int lane = tid & 63, wv = tid >> 6, grp = lane >> 4, lrow = lane & 15;
    const size_t nbase = (size_t)n * TLN;
    const int qq = q0 + wv * 16 + lrow;

    s8 gf[4];
    #pragma unroll
    for (int kk = 0; kk < 4; ++kk)
        gf[kk] = *reinterpret_cast<const s8*>(
            bufA + nbase + (size_t)(kk * 4 + grp) * 8192 + (size_t)qq * 8);

    f4 C[8];
    #pragma unroll
    for (int et = 0; et < 8; ++et) C[et] = (f4)0.f;
    #pragma unroll
    for (int kk = 0; kk < 4; ++kk) {
        const int kb = kk * 32 + grp * 8;
        #pragma unroll
        for (int et = 0; et < 8; ++et) {
            s8 wf = *reinterpret_cast<const s8*>(WoS + (size_t)(et * 16 + lrow) * D_MODEL + kb);
            C[et] = MFMA(gf[kk], wf, C[et], 0, 0, 0);
        }
    }

    #pragma unroll
    for (int et = 0; et < 8; ++et)
        #pragma unroll
        for (int i = 0; i < 4; ++i)
            Xs[wv * 16 + grp * 4 + i][et * 16 + lrow] = f2b(C[et][i]);
    __syncthreads();

    gates_from_lds_TL(Xs, WiT, bufA, bufB, nbase, q0, tid);
}

// ---------------------------------------------------------------------------
// tscan: causal scan over T on TL layout, FUSED og gating: writes
// G2 = og_T * S_T (bf16) in place over iu_T. Thread per (b,oct,q).
// ---------------------------------------------------------------------------
__global__ __launch_bounds__(256) void tscan_kernel(
    ushort* __restrict__ buf, const ushort* __restrict__ og,
    const float* __restrict__ Av)
{
    const int tid = blockIdx.x * 256 + threadIdx.x;   // 131072
    const int q   = tid & 1023;
    const int oct = (tid >> 10) & 15;
    const int b   = tid >> 14;
    float aa[8], st[8];
    #pragma unroll
    for (int jj = 0; jj < 8; ++jj) {
        aa[jj] = fminf(__expf(Av[oct * 8 + jj]), 0.999f);
        st[jj] = 0.f;
    }
    const size_t base = (size_t)(b * T_) * TLN + (size_t)oct * 8192 + (size_t)q * 8;
    #pragma unroll
    for (int t = 0; t < T_; ++t) {
        const size_t off = base + (size_t)t * TLN;
        us8 v = *reinterpret_cast<us8*>(buf + off);
        us8 o = *reinterpret_cast<const us8*>(og + off);
        us8 w;
        #pragma unroll
        for (int jj = 0; jj < 8; ++jj) {
            st[jj] = fmaf(aa[jj], st[jj], b2f(v[jj]));
            w[jj] = f2b(st[jj] * b2f(o[jj]));
        }
        *reinterpret_cast<us8*>(buf + off) = w;
    }
}

// ---------------------------------------------------------------------------
// fusedB: y = WoT @ G2 (G2 pre-gated by tscan -> RAW 16B A-fragments, zero
// conversion VALU), resid PREFETCHED before the GEMM; X = resid + y; then
// next-layer spatial gates (GATES) or fused LayerNorm (LN). 2048 blocks.
// ---------------------------------------------------------------------------
template <bool GATES, bool LN>
__global__ __launch_bounds__(256, 3) void fusedB_kernel(
    ushort* bufA /* in: G2, out: iu_S */, ushort* bufB /* out: og_S */,
    const ushort* __restrict__ WoT, const float* __restrict__ resid,
    float* __restrict__ X, const ushort* __restrict__ WiS2,
    const float* __restrict__ lng, const float* __restrict__ lnb)
{
    __shared__ ushort Xs[64][136];
    const int n   = blockIdx.x >> 4;
    const int q0  = (blockIdx.x & 15) << 6;
    const int tid = threadIdx.x;
    const int lane = tid & 63, wv = tid >> 6, grp = lane >> 4, lrow = lane & 15;
    const size_t nbase = (size_t)n * TLN;
    const int qq = q0 + wv * 16 + lrow;
    const int qb = q0 + wv * 16 + grp * 4;   // 4 consecutive q per lane

    // A-fragments: raw pre-gated bf16, no conversion
    s8 g[4];
    #pragma unroll
    for (int kk = 0; kk < 4; ++kk)
        g[kk] = *reinterpret_cast<const s8*>(
            bufA + nbase + (size_t)(kk * 4 + grp) * 8192 + (size_t)qq * 8);

    // prefetch residual (independent) — hides under the GEMM
    f4 r[8];
    #pragma unroll
    for (int et = 0; et < 8; ++et)
        r[et] = *reinterpret_cast<const f4*>(resid + nbase + (size_t)(et * 16 + lrow) * HW + qb);

    f4 C[8];
    #pragma unroll
    for (int et = 0; et < 8; ++et) C[et] = (f4)0.f;
    #pragma unroll
    for (int kk = 0; kk < 4; ++kk) {
        const int kb = kk * 32 + grp * 8;
        #pragma unroll
        for (int et = 0; et < 8; ++et) {
            s8 wf = *reinterpret_cast<const s8*>(WoT + (size_t)(et * 16 + lrow) * D_MODEL + kb);
            C[et] = MFMA(g[kk], wf, C[et], 0, 0, 0);
        }
    }

    #pragma unroll
    for (int et = 0; et < 8; ++et)
        #pragma unroll
        for (int i = 0; i < 4; ++i) C[et][i] += r[et][i];

    if constexpr (LN) {
        float s4[4] = {0.f,0.f,0.f,0.f}, q4[4] = {0.f,0.f,0.f,0.f};
        #pragma unroll
        for (int et = 0; et < 8; ++et)
            #pragma unroll
            for (int i = 0; i < 4; ++i) {
                s4[i] += C[et][i];
                q4[i] += C[et][i] * C[et][i];
            }
        #pragma unroll
        for (int m = 1; m <= 8; m <<= 1)
            #pragma unroll
            for (int i = 0; i < 4; ++i) {
                s4[i] += __shfl_xor(s4[i], m);
                q4[i] += __shfl_xor(q4[i], m);
            }
        float mean[4], rstd[4];
        #pragma unroll
        for (int i = 0; i < 4; ++i) {
            mean[i] = s4[i] * (1.f / D_MODEL);
            rstd[i] = rsqrtf(q4[i] * (1.f / D_MODEL) - mean[i] * mean[i] + LN_EPSF);
        }
        #pragma unroll
        for (int et = 0; et < 8; ++et) {
            const int e = et * 16 + lrow;
            const float ge = lng[e], be = lnb[e];
            const size_t offX = nbase + (size_t)e * HW + qb;
            f4 o;
            #pragma unroll
            for (int i = 0; i < 4; ++i)
                o[i] = (C[et][i] - mean[i]) * rstd[i] * ge + be;
            *reinterpret_cast<f4*>(X + offX) = o;
        }
    } else {
        #pragma unroll
        for (int et = 0; et < 8; ++et) {
            const int e = et * 16 + lrow;
            const size_t offX = nbase + (size_t)e * HW + qb;
            f4 v;
            #pragma unroll
            for (int i = 0; i < 4; ++i) v[i] = C[et][i];
            *reinterpret_cast<f4*>(X + offX) = v;
            if constexpr (GATES) {
                #pragma unroll
                for (int i = 0; i < 4; ++i)
                    Xs[wv * 16 + grp * 4 + i][e] = f2b(v[i]);
            }
        }
        if constexpr (GATES) {
            __syncthreads();
            gates_from_lds_TL(Xs, WiS2, bufA, bufB, nbase, q0, tid);
        }
    }
}

// ---------------------------------------------------------------------------
extern "C" void kernel_launch(void* const* d_in, const int* in_sizes, int n_in,
                              void* d_out, int out_size, void* d_ws, size_t ws_size,
                              hipStream_t stream) {
    const float* tok   = (const float*)d_in[0];
    const float* s_inp = (const float*)d_in[1];
    const float* s_A   = (const float*)d_in[2];
    const float* s_out = (const float*)d_in[3];
    const float* t_inp = (const float*)d_in[4];
    const float* t_A   = (const float*)d_in[5];
    const float* t_out = (const float*)d_in[6];
    const float* ln_g  = (const float*)d_in[7];
    const float* ln_b  = (const float*)d_in[8];

    float*  X    = (float*)d_out;                    // residual stream fp32 [n][d][q]
    ushort* Abuf = (ushort*)d_ws;                    // 32MB bf16 tiled (iu / G / G2)
    ushort* Bbuf = Abuf + (size_t)16777216;          // 32MB bf16 tiled (og)
    ushort* Wbf  = Bbuf + (size_t)16777216;          // ~1MB bf16 weights
    ushort* sWiB = Wbf;
    ushort* sWoB = Wbf + 196608;
    ushort* tWiB = Wbf + 262144;
    ushort* tWoB = Wbf + 458752;

    const dim3 blk256(256);

    wconv_kernel<<<768, blk256, 0, stream>>>(s_inp, sWiB, 196608);
    wconv_kernel<<<256, blk256, 0, stream>>>(s_out, sWoB, 65536);
    wconv_kernel<<<768, blk256, 0, stream>>>(t_inp, tWiB, 196608);
    wconv_kernel<<<256, blk256, 0, stream>>>(t_out, tWoB, 65536);

    // layer-0 spatial gates from tok
    gates_f32_kernel<<<2048, blk256, 0, stream>>>(tok, sWiB, Abuf, Bbuf);

    for (int l = 0; l < DEPTH; ++l) {
        const float* xin = (l == 0) ? tok : X;

        scan2d_kernel<<<2048, blk256, 0, stream>>>(Abuf, Bbuf, s_A + (size_t)l * 128);
        fusedA_kernel<<<2048, blk256, 0, stream>>>(
            Abuf, Bbuf, sWoB + (size_t)l * 16384, tWiB + (size_t)l * 49152);
        tscan_kernel<<<512, blk256, 0, stream>>>(Abuf, Bbuf, t_A + (size_t)l * 128);

        if (l < DEPTH - 1) {
            fusedB_kernel<true, false><<<2048, blk256, 0, stream>>>(
                Abuf, Bbuf, tWoB + (size_t)l * 16384, xin, X,
                sWiB + (size_t)(l + 1) * 49152, nullptr, nullptr);
        } else {
            fusedB_kernel<false, true><<<2048, blk256, 0, stream>>>(
                Abuf, Bbuf, tWoB + (size_t)l * 16384, xin, X,
                nullptr, ln_g, ln_b);
        }
    }
}

// Round 12
// 682.712 us; speedup vs baseline: 1.1323x; 1.1323x over previous
//
#include <hip/hip_runtime.h>
#include <hip/hip_bf16.h>
#include <math.h>

#define D_MODEL 128
#define HW      1024
#define DEPTH   4
#define NIMG    128   // B*T
#define B_      8
#define T_      16
#define LN_EPSF 1e-5f
#define TLN     131072   // elements per image (128*1024)
#define PS      1033     // scan LDS plane stride (dwords)

typedef short  s8  __attribute__((ext_vector_type(8)));
typedef ushort us8 __attribute__((ext_vector_type(8)));
typedef ushort us4 __attribute__((ext_vector_type(4)));
typedef float  f4  __attribute__((ext_vector_type(4)));

#define MFMA __builtin_amdgcn_mfma_f32_16x16x32_bf16

__device__ __forceinline__ float sig_(float x) { return 1.0f / (1.0f + __expf(-x)); }
__device__ __forceinline__ float tanh_(float x) { return 2.0f * sig_(2.0f * x) - 1.0f; }
__device__ __forceinline__ ushort f2b(float f) {
    __hip_bfloat16 h = __float2bfloat16(f);
    return *reinterpret_cast<ushort*>(&h);
}
__device__ __forceinline__ float b2f(ushort u) {
    __hip_bfloat16 h = *reinterpret_cast<__hip_bfloat16*>(&u);
    return __bfloat162float(h);
}

// ---------------------------------------------------------------------------
// wconv: fp32 -> bf16 weight pre-conversion
// ---------------------------------------------------------------------------
__global__ __launch_bounds__(256) void wconv_kernel(
    const float* __restrict__ src, ushort* __restrict__ dst, int n)
{
    int i = blockIdx.x * 256 + threadIdx.x;
    if (i < n) dst[i] = f2b(src[i]);
}

// ---------------------------------------------------------------------------
// Two-phase 3-gate GEMM from LDS tile Xs[q][d] (bf16). Orientation:
// aU[mt][nt] = MFMA(xa[mt], w[nt]) -> C col=lane&15 -> e, row -> q.
// Stores iu/og to [n][ch][q] (us4 along q). Phase 1 = U,I; phase 2 = O
// (halves peak accumulator registers -> 3 blocks/CU).
// ---------------------------------------------------------------------------
__device__ __forceinline__ void gates_from_lds(
    const ushort (*Xs)[136], const ushort* __restrict__ Wi,
    ushort* __restrict__ iu, ushort* __restrict__ og,
    size_t nbase, int q0, int tid)
{
    const int lane = tid & 63, wv = tid >> 6, grp = lane >> 4, lrow = lane & 15;
    const int ch0 = wv * 32;

    // ---- phase 1: U and I ----
    {
        f4 aU[4][2], aI[4][2];
        #pragma unroll
        for (int mt = 0; mt < 4; ++mt)
            #pragma unroll
            for (int nt = 0; nt < 2; ++nt) { aU[mt][nt] = (f4)0.f; aI[mt][nt] = (f4)0.f; }

        #pragma unroll
        for (int kk = 0; kk < 4; ++kk) {
            const int kb = kk * 32 + grp * 8;
            s8 xa[4], wu[2], wi[2];
            #pragma unroll
            for (int mt = 0; mt < 4; ++mt)
                xa[mt] = *reinterpret_cast<const s8*>(&Xs[mt * 16 + lrow][kb]);
            #pragma unroll
            for (int nt = 0; nt < 2; ++nt) {
                const int e = ch0 + nt * 16 + lrow;
                wu[nt] = *reinterpret_cast<const s8*>(Wi + (size_t)e * D_MODEL + kb);
                wi[nt] = *reinterpret_cast<const s8*>(Wi + (size_t)(e + 128) * D_MODEL + kb);
            }
            #pragma unroll
            for (int mt = 0; mt < 4; ++mt)
                #pragma unroll
                for (int nt = 0; nt < 2; ++nt) {
                    aU[mt][nt] = MFMA(xa[mt], wu[nt], aU[mt][nt], 0, 0, 0);
                    aI[mt][nt] = MFMA(xa[mt], wi[nt], aI[mt][nt], 0, 0, 0);
                }
        }
        #pragma unroll
        for (int mt = 0; mt < 4; ++mt)
            #pragma unroll
            for (int nt = 0; nt < 2; ++nt) {
                const int e = ch0 + nt * 16 + lrow;
                const size_t off = nbase + (size_t)e * HW + q0 + mt * 16 + grp * 4;
                us4 piu;
                #pragma unroll
                for (int i = 0; i < 4; ++i)
                    piu[i] = f2b(sig_(aI[mt][nt][i]) * tanh_(aU[mt][nt][i]));
                *reinterpret_cast<us4*>(iu + off) = piu;
            }
    }
    // ---- phase 2: O ----
    {
        f4 aO[4][2];
        #pragma unroll
        for (int mt = 0; mt < 4; ++mt)
            #pragma unroll
            for (int nt = 0; nt < 2; ++nt) aO[mt][nt] = (f4)0.f;

        #pragma unroll
        for (int kk = 0; kk < 4; ++kk) {
            const int kb = kk * 32 + grp * 8;
            s8 xa[4], wo[2];
            #pragma unroll
            for (int mt = 0; mt < 4; ++mt)
                xa[mt] = *reinterpret_cast<const s8*>(&Xs[mt * 16 + lrow][kb]);
            #pragma unroll
            for (int nt = 0; nt < 2; ++nt)
                wo[nt] = *reinterpret_cast<const s8*>(Wi + (size_t)(ch0 + nt * 16 + lrow + 256) * D_MODEL + kb);
            #pragma unroll
            for (int mt = 0; mt < 4; ++mt)
                #pragma unroll
                for (int nt = 0; nt < 2; ++nt)
                    aO[mt][nt] = MFMA(xa[mt], wo[nt], aO[mt][nt], 0, 0, 0);
        }
        #pragma unroll
        for (int mt = 0; mt < 4; ++mt)
            #pragma unroll
            for (int nt = 0; nt < 2; ++nt) {
                const int e = ch0 + nt * 16 + lrow;
                const size_t off = nbase + (size_t)e * HW + q0 + mt * 16 + grp * 4;
                us4 pog;
                #pragma unroll
                for (int i = 0; i < 4; ++i)
                    pog[i] = f2b(sig_(aO[mt][nt][i]));
                *reinterpret_cast<us4*>(og + off) = pog;
            }
    }
}

// ---------------------------------------------------------------------------
// gates_f32: layer-0 spatial gates from fp32 tok [n][d][q].
// Coalesced f4 loads (16 threads/row, 256B runs) + LDS-side transpose.
// ---------------------------------------------------------------------------
__global__ __launch_bounds__(256, 3) void gates_f32_kernel(
    const float* __restrict__ in, const ushort* __restrict__ Wi,
    ushort* __restrict__ iu, ushort* __restrict__ og)
{
    __shared__ ushort Xs[64][136];
    const int n   = blockIdx.x >> 4;
    const int q0  = (blockIdx.x & 15) << 6;
    const int tid = threadIdx.x;
    const size_t nbase = (size_t)n * TLN;

    #pragma unroll
    for (int it = 0; it < 8; ++it) {
        const int c  = it * 256 + tid;     // 0..2047
        const int ch = c >> 4;
        const int qo = c & 15;
        f4 v = *reinterpret_cast<const f4*>(in + nbase + (size_t)ch * HW + q0 + qo * 4);
        #pragma unroll
        for (int j = 0; j < 4; ++j) Xs[qo * 4 + j][ch] = f2b(v[j]);
    }
    __syncthreads();
    gates_from_lds(Xs, Wi, iu, og, nbase, q0, tid);
}

// ---------------------------------------------------------------------------
// scan2d: block=(n, ch-octet). Coalesced us8 slab loads (q-contiguous rows)
// -> swizzled fp32 LDS planes; row scans -> R; col scans + R -> S; writes
// G = og * S * 0.25 (bf16) in place over iu. og prefetched at entry.
// ---------------------------------------------------------------------------
__global__ __launch_bounds__(256, 2) void scan2d_kernel(
    ushort* bufG /* in: iu, out: G */, const ushort* __restrict__ og,
    const float* __restrict__ Av)
{
    __shared__ float P[8 * PS];
    __shared__ float R[8 * PS];
    const int n   = blockIdx.x >> 4;
    const int oct = blockIdx.x & 15;
    const int tid = threadIdx.x;
    const size_t base = (size_t)n * TLN + (size_t)(oct * 8) * HW;

    // prefetch og tile (consumed in phase 4)
    us8 ogv[4];
    #pragma unroll
    for (int it = 0; it < 4; ++it) {
        const int c  = it * 256 + tid;     // 0..1023
        const int dc = c >> 7, po = c & 127;
        ogv[it] = *reinterpret_cast<const us8*>(og + base + (size_t)dc * HW + po * 8);
    }

    // slab load iu -> swizzled planes
    #pragma unroll
    for (int it = 0; it < 4; ++it) {
        const int c  = it * 256 + tid;
        const int dc = c >> 7, po = c & 127;
        us8 v = *reinterpret_cast<const us8*>(bufG + base + (size_t)dc * HW + po * 8);
        #pragma unroll
        for (int j = 0; j < 8; ++j) {
            const int p = po * 8 + j;
            P[dc * PS + (p ^ (((p >> 5) & 7) << 2))] = b2f(v[j]);
        }
    }
    __syncthreads();

    const int dc  = tid & 7;
    const int row = tid >> 3;
    const float a = fminf(__expf(Av[oct * 8 + dc]), 0.999f);

    {   // row scans (lr+rl) -> R
        const int swb = (row * 32) ^ ((row & 7) << 2);
        float x[32], r[32];
        #pragma unroll
        for (int j = 0; j < 32; ++j) x[j] = P[dc * PS + (swb ^ j)];
        float s = 0.f;
        #pragma unroll
        for (int j = 0; j < 32; ++j) { s = fmaf(a, s, x[j]); r[j] = s; }
        s = 0.f;
        #pragma unroll
        for (int j = 31; j >= 0; --j) { s = fmaf(a, s, x[j]); r[j] += s; }
        #pragma unroll
        for (int j = 0; j < 32; ++j) R[dc * PS + (swb ^ j)] = r[j];
    }
    __syncthreads();

    {   // col scans (ud+du) + R -> P
        float x[32], t[32];
        #pragma unroll
        for (int i = 0; i < 32; ++i) {
            const int p = i * 32 + row;
            x[i] = P[dc * PS + (p ^ ((i & 7) << 2))];
        }
        float s = 0.f;
        #pragma unroll
        for (int i = 0; i < 32; ++i) { s = fmaf(a, s, x[i]); t[i] = s; }
        s = 0.f;
        #pragma unroll
        for (int i = 31; i >= 0; --i) { s = fmaf(a, s, x[i]); t[i] += s; }
        #pragma unroll
        for (int i = 0; i < 32; ++i) {
            const int idx = dc * PS + ((i * 32 + row) ^ ((i & 7) << 2));
            P[idx] = t[i] + R[idx];
        }
    }
    __syncthreads();

    // write G = og * S * 0.25 (in place)
    #pragma unroll
    for (int it = 0; it < 4; ++it) {
        const int c  = it * 256 + tid;
        const int dc2 = c >> 7, po = c & 127;
        us8 w;
        #pragma unroll
        for (int j = 0; j < 8; ++j) {
            const int p = po * 8 + j;
            w[j] = f2b(b2f(ogv[it][j]) * P[dc2 * PS + (p ^ (((p >> 5) & 7) << 2))] * 0.25f);
        }
        *reinterpret_cast<us8*>(bufG + base + (size_t)dc2 * HW + po * 8) = w;
    }
}

// ---------------------------------------------------------------------------
// fusedA: stage G (pre-gated, coalesced us8 + LDS transpose) -> xs = WoS @ G
// (kept in LDS) -> temporal 3-gate GEMM -> iu_T/og_T. In-place safe.
// ---------------------------------------------------------------------------
__global__ __launch_bounds__(256, 3) void fusedA_kernel(
    ushort* bufA /* in: G, out: iu_T */, ushort* bufB /* out: og_T */,
    const ushort* __restrict__ WoS, const ushort* __restrict__ WiT)
{
    __shared__ ushort Gs[64][136];
    const int n   = blockIdx.x >> 4;
    const int q0  = (blockIdx.x & 15) << 6;
    const int tid = threadIdx.x;
    const int lane = tid & 63, wv = tid >> 6, grp = lane >> 4, lrow = lane & 15;
    const int ch0 = wv * 32;
    const size_t nbase = (size_t)n * TLN;

    #pragma unroll
    for (int it = 0; it < 4; ++it) {
        const int c  = it * 256 + tid;     // 0..1023
        const int ch = c >> 3, qo = c & 7;
        us8 v = *reinterpret_cast<const us8*>(bufA + nbase + (size_t)ch * HW + q0 + qo * 8);
        #pragma unroll
        for (int j = 0; j < 8; ++j) Gs[qo * 8 + j][ch] = v[j];
    }
    __syncthreads();

    // xs = WoS @ G  (C: row=e, col=q) -> us4 LDS write as [q][e]
    f4 c1[2][4];
    #pragma unroll
    for (int et = 0; et < 2; ++et)
        #pragma unroll
        for (int qt = 0; qt < 4; ++qt) c1[et][qt] = (f4)0.f;

    #pragma unroll
    for (int kk = 0; kk < 4; ++kk) {
        const int kb = kk * 32 + grp * 8;
        s8 wf[2], xg[4];
        #pragma unroll
        for (int et = 0; et < 2; ++et)
            wf[et] = *reinterpret_cast<const s8*>(WoS + (size_t)(ch0 + et * 16 + lrow) * D_MODEL + kb);
        #pragma unroll
        for (int qt = 0; qt < 4; ++qt)
            xg[qt] = *reinterpret_cast<const s8*>(&Gs[qt * 16 + lrow][kb]);
        #pragma unroll
        for (int et = 0; et < 2; ++et)
            #pragma unroll
            for (int qt = 0; qt < 4; ++qt)
                c1[et][qt] = MFMA(wf[et], xg[qt], c1[et][qt], 0, 0, 0);
    }
    __syncthreads();   // all Gs reads done

    #pragma unroll
    for (int et = 0; et < 2; ++et)
        #pragma unroll
        for (int qt = 0; qt < 4; ++qt) {
            us4 pk;
            #pragma unroll
            for (int i = 0; i < 4; ++i) pk[i] = f2b(c1[et][qt][i]);
            *reinterpret_cast<us4*>(&Gs[qt * 16 + lrow][ch0 + et * 16 + grp * 4]) = pk;
        }
    __syncthreads();

    gates_from_lds(Gs, WiT, bufA, bufB, nbase, q0, tid);
}

// ---------------------------------------------------------------------------
// tscan: causal scan over T in place, [n][ch][q], us8 (8 consecutive q).
// ---------------------------------------------------------------------------
__global__ __launch_bounds__(256) void tscan_kernel(
    ushort* __restrict__ buf, const float* __restrict__ Av)
{
    const int tid = blockIdx.x * 256 + threadIdx.x;   // 131072
    const int qo = tid & 127;
    const int d  = (tid >> 7) & 127;
    const int b  = tid >> 14;
    const float a = fminf(__expf(Av[d]), 0.999f);
    const size_t base = (size_t)(b * T_) * TLN + (size_t)d * HW + qo * 8;
    float st[8];
    #pragma unroll
    for (int j = 0; j < 8; ++j) st[j] = 0.f;
    #pragma unroll
    for (int t = 0; t < T_; ++t) {
        ushort* p = buf + base + (size_t)t * TLN;
        us8 v = *reinterpret_cast<us8*>(p);
        us8 w;
        #pragma unroll
        for (int j = 0; j < 8; ++j) {
            st[j] = fmaf(a, st[j], b2f(v[j]));
            w[j] = f2b(st[j]);
        }
        *reinterpret_cast<us8*>(p) = w;
    }
}

// ---------------------------------------------------------------------------
// fusedB (mid layers): stage gated product og_T*S_T (coalesced) -> LDS,
// y = WoT @ G2, X = resid + y (resid prefetched), next-layer spatial gates.
// ---------------------------------------------------------------------------
__global__ __launch_bounds__(256, 3) void fusedB_kernel(
    ushort* bufA /* in: S_T, out: iu_S */, ushort* bufB /* in: og_T, out: og_S */,
    const ushort* __restrict__ WoT, const float* __restrict__ resid,
    float* __restrict__ X, const ushort* __restrict__ WiS2)
{
    __shared__ ushort Gs[64][136];
    const int n   = blockIdx.x >> 4;
    const int q0  = (blockIdx.x & 15) << 6;
    const int tid = threadIdx.x;
    const int lane = tid & 63, wv = tid >> 6, grp = lane >> 4, lrow = lane & 15;
    const int ch0 = wv * 32;
    const size_t nbase = (size_t)n * TLN;

    #pragma unroll
    for (int it = 0; it < 4; ++it) {
        const int c  = it * 256 + tid;
        const int ch = c >> 3, qo = c & 7;
        const size_t o = nbase + (size_t)ch * HW + q0 + qo * 8;
        us8 sv = *reinterpret_cast<const us8*>(bufA + o);
        us8 ov = *reinterpret_cast<const us8*>(bufB + o);
        #pragma unroll
        for (int j = 0; j < 8; ++j) Gs[qo * 8 + j][ch] = f2b(b2f(sv[j]) * b2f(ov[j]));
    }

    // prefetch residual (independent of LDS)
    f4 r[4][2];
    #pragma unroll
    for (int mt = 0; mt < 4; ++mt)
        #pragma unroll
        for (int nt = 0; nt < 2; ++nt)
            r[mt][nt] = *reinterpret_cast<const f4*>(
                resid + nbase + (size_t)(ch0 + nt * 16 + lrow) * HW + q0 + mt * 16 + grp * 4);
    __syncthreads();

    // y = WoT @ G2  (C: row=q, col=e) -> f4 X stores along q
    f4 C[4][2];
    #pragma unroll
    for (int mt = 0; mt < 4; ++mt)
        #pragma unroll
        for (int nt = 0; nt < 2; ++nt) C[mt][nt] = (f4)0.f;

    #pragma unroll
    for (int kk = 0; kk < 4; ++kk) {
        const int kb = kk * 32 + grp * 8;
        s8 xg[4], wf[2];
        #pragma unroll
        for (int mt = 0; mt < 4; ++mt)
            xg[mt] = *reinterpret_cast<const s8*>(&Gs[mt * 16 + lrow][kb]);
        #pragma unroll
        for (int nt = 0; nt < 2; ++nt)
            wf[nt] = *reinterpret_cast<const s8*>(WoT + (size_t)(ch0 + nt * 16 + lrow) * D_MODEL + kb);
        #pragma unroll
        for (int mt = 0; mt < 4; ++mt)
            #pragma unroll
            for (int nt = 0; nt < 2; ++nt)
                C[mt][nt] = MFMA(xg[mt], wf[nt], C[mt][nt], 0, 0, 0);
    }
    __syncthreads();   // Gs reads done before overwrite

    #pragma unroll
    for (int mt = 0; mt < 4; ++mt)
        #pragma unroll
        for (int nt = 0; nt < 2; ++nt) {
            const int e    = ch0 + nt * 16 + lrow;
            const int qloc = mt * 16 + grp * 4;
            const size_t off = nbase + (size_t)e * HW + q0 + qloc;
            f4 v;
            #pragma unroll
            for (int i = 0; i < 4; ++i) v[i] = C[mt][nt][i] + r[mt][nt][i];
            *reinterpret_cast<f4*>(X + off) = v;
            #pragma unroll
            for (int i = 0; i < 4; ++i) Gs[qloc + i][e] = f2b(v[i]);
        }
    __syncthreads();
    gates_from_lds(Gs, WiS2, bufA, bufB, nbase, q0, tid);
}

// ---------------------------------------------------------------------------
// fusedB_ln (last layer): wave owns 16 q x all 128 e -> LN is wave-local.
// ---------------------------------------------------------------------------
__global__ __launch_bounds__(256, 3) void fusedB_ln_kernel(
    const ushort* __restrict__ bufA, const ushort* __restrict__ bufB,
    const ushort* __restrict__ WoT, const float* __restrict__ resid,
    float* __restrict__ X,
    const float* __restrict__ lng, const float* __restrict__ lnb)
{
    __shared__ ushort Gs[64][136];
    const int n   = blockIdx.x >> 4;
    const int q0  = (blockIdx.x & 15) << 6;
    const int tid = threadIdx.x;
    const int lane = tid & 63, wv = tid >> 6, grp = lane >> 4, lrow = lane & 15;
    const size_t nbase = (size_t)n * TLN;

    #pragma unroll
    for (int it = 0; it < 4; ++it) {
        const int c  = it * 256 + tid;
        const int ch = c >> 3, qo = c & 7;
        const size_t o = nbase + (size_t)ch * HW + q0 + qo * 8;
        us8 sv = *reinterpret_cast<const us8*>(bufA + o);
        us8 ov = *reinterpret_cast<const us8*>(bufB + o);
        #pragma unroll
        for (int j = 0; j < 8; ++j) Gs[qo * 8 + j][ch] = f2b(b2f(sv[j]) * b2f(ov[j]));
    }

    const int qb = q0 + wv * 16 + grp * 4;
    f4 r[8];
    #pragma unroll
    for (int et = 0; et < 8; ++et)
        r[et] = *reinterpret_cast<const f4*>(
            resid + nbase + (size_t)(et * 16 + lrow) * HW + qb);
    __syncthreads();

    // y = WoT @ G2, wave q-slice = wv*16..+16 (C: row=q, col=e)
    f4 C[8];
    #pragma unroll
    for (int et = 0; et < 8; ++et) C[et] = (f4)0.f;
    #pragma unroll
    for (int kk = 0; kk < 4; ++kk) {
        const int kb = kk * 32 + grp * 8;
        s8 xa = *reinterpret_cast<const s8*>(&Gs[wv * 16 + lrow][kb]);
        #pragma unroll
        for (int et = 0; et < 8; ++et) {
            s8 wf = *reinterpret_cast<const s8*>(WoT + (size_t)(et * 16 + lrow) * D_MODEL + kb);
            C[et] = MFMA(xa, wf, C[et], 0, 0, 0);
        }
    }

    float s4[4] = {0.f,0.f,0.f,0.f}, q4[4] = {0.f,0.f,0.f,0.f};
    #pragma unroll
    for (int et = 0; et < 8; ++et)
        #pragma unroll
        for (int i = 0; i < 4; ++i) {
            const float v = C[et][i] + r[et][i];
            C[et][i] = v;
            s4[i] += v; q4[i] += v * v;
        }
    #pragma unroll
    for (int m = 1; m <= 8; m <<= 1)
        #pragma unroll
        for (int i = 0; i < 4; ++i) {
            s4[i] += __shfl_xor(s4[i], m);
            q4[i] += __shfl_xor(q4[i], m);
        }
    float mean[4], rstd[4];
    #pragma unroll
    for (int i = 0; i < 4; ++i) {
        mean[i] = s4[i] * (1.f / D_MODEL);
        rstd[i] = rsqrtf(q4[i] * (1.f / D_MODEL) - mean[i] * mean[i] + LN_EPSF);
    }
    #pragma unroll
    for (int et = 0; et < 8; ++et) {
        const int e = et * 16 + lrow;
        const float ge = lng[e], be = lnb[e];
        const size_t off = nbase + (size_t)e * HW + qb;
        f4 o;
        #pragma unroll
        for (int i = 0; i < 4; ++i)
            o[i] = (C[et][i] - mean[i]) * rstd[i] * ge + be;
        *reinterpret_cast<f4*>(X + off) = o;
    }
}

// ---------------------------------------------------------------------------
extern "C" void kernel_launch(void* const* d_in, const int* in_sizes, int n_in,
                              void* d_out, int out_size, void* d_ws, size_t ws_size,
                              hipStream_t stream) {
    const float* tok   = (const float*)d_in[0];
    const float* s_inp = (const float*)d_in[1];
    const float* s_A   = (const float*)d_in[2];
    const float* s_out = (const float*)d_in[3];
    const float* t_inp = (const float*)d_in[4];
    const float* t_A   = (const float*)d_in[5];
    const float* t_out = (const float*)d_in[6];
    const float* ln_g  = (const float*)d_in[7];
    const float* ln_b  = (const float*)d_in[8];

    float*  X    = (float*)d_out;                    // residual stream fp32 [n][d][q]
    ushort* Abuf = (ushort*)d_ws;                    // 32MB bf16 [n][ch][q] (iu / G / S)
    ushort* Bbuf = Abuf + (size_t)16777216;          // 32MB bf16 [n][ch][q] (og)
    ushort* Wbf  = Bbuf + (size_t)16777216;          // ~1MB bf16 weights
    ushort* sWiB = Wbf;
    ushort* sWoB = Wbf + 196608;
    ushort* tWiB = Wbf + 262144;
    ushort* tWoB = Wbf + 458752;

    const dim3 blk256(256);

    wconv_kernel<<<768, blk256, 0, stream>>>(s_inp, sWiB, 196608);
    wconv_kernel<<<256, blk256, 0, stream>>>(s_out, sWoB, 65536);
    wconv_kernel<<<768, blk256, 0, stream>>>(t_inp, tWiB, 196608);
    wconv_kernel<<<256, blk256, 0, stream>>>(t_out, tWoB, 65536);

    // layer-0 spatial gates from tok
    gates_f32_kernel<<<2048, blk256, 0, stream>>>(tok, sWiB, Abuf, Bbuf);

    for (int l = 0; l < DEPTH; ++l) {
        const float* xin = (l == 0) ? tok : X;

        scan2d_kernel<<<2048, blk256, 0, stream>>>(Abuf, Bbuf, s_A + (size_t)l * 128);
        fusedA_kernel<<<2048, blk256, 0, stream>>>(
            Abuf, Bbuf, sWoB + (size_t)l * 16384, tWiB + (size_t)l * 49152);
        tscan_kernel<<<512, blk256, 0, stream>>>(Abuf, t_A + (size_t)l * 128);

        if (l < DEPTH - 1) {
            fusedB_kernel<<<2048, blk256, 0, stream>>>(
                Abuf, Bbuf, tWoB + (size_t)l * 16384, xin, X,
                sWiB + (size_t)(l + 1) * 49152);
        } else {
            fusedB_ln_kernel<<<2048, blk256, 0, stream>>>(
                Abuf, Bbuf, tWoB + (size_t)l * 16384, xin, X, ln_g, ln_b);
        }
    }
}